// Round 2
// baseline (441.342 us; speedup 1.0000x reference)
//
#include <hip/hip_runtime.h>
#include <math.h>

#define N_NODES 8192
#define N_EDGES 262144
#define DIM 256
#define OUTD 64

// ---------------- CSR build ----------------

__global__ __launch_bounds__(256) void hist_kernel(const int* __restrict__ dst,
                                                   int* __restrict__ cnt) {
    int e = blockIdx.x * 256 + threadIdx.x;
    if (e < N_EDGES) atomicAdd(&cnt[dst[e]], 1);
}

__global__ __launch_bounds__(256) void dinv_kernel(const int* __restrict__ cnt,
                                                   float* __restrict__ dinv) {
    int i = blockIdx.x * 256 + threadIdx.x;
    if (i < N_NODES) dinv[i] = rsqrtf((float)(cnt[i] + 1));  // +1 self-loop
}

// single-block exclusive scan of cnt[8192] -> off[0..8192]
__global__ __launch_bounds__(256) void scan_kernel(const int* __restrict__ cnt,
                                                   int* __restrict__ off) {
    __shared__ int sums[256];
    int tid = threadIdx.x;
    int base = tid * 32;
    int local[32];
    int s = 0;
#pragma unroll
    for (int i = 0; i < 32; ++i) { local[i] = s; s += cnt[base + i]; }
    sums[tid] = s;
    __syncthreads();
    for (int d = 1; d < 256; d <<= 1) {
        int v = (tid >= d) ? sums[tid - d] : 0;
        __syncthreads();
        sums[tid] += v;
        __syncthreads();
    }
    int pre = (tid == 0) ? 0 : sums[tid - 1];
#pragma unroll
    for (int i = 0; i < 32; ++i) off[base + i] = pre + local[i];
    if (tid == 255) off[N_NODES] = pre + s;
}

__global__ __launch_bounds__(256) void fill_kernel(const int* __restrict__ src,
                                                   const int* __restrict__ dst,
                                                   const int* __restrict__ off,
                                                   int* __restrict__ cursor,
                                                   int* __restrict__ csr_src) {
    int e = blockIdx.x * 256 + threadIdx.x;
    if (e < N_EDGES) {
        int d = dst[e];
        int p = atomicAdd(&cursor[d], 1);
        csr_src[off[d] + p] = src[e];
    }
}

// ---------------- dense GEMM: C[M,N] = A[M,K] @ W[K,N] (+ bias) ----------------
// 64x64 tile, 256 threads, 4x4 register blocking, BK=32.

__global__ __launch_bounds__(256) void gemm_f32(const float* __restrict__ A,
                                                const float* __restrict__ W,
                                                const float* __restrict__ bias,
                                                float* __restrict__ C,
                                                int M, int N, int K) {
    __shared__ float Ast[32][68];  // transposed A tile [k][row], padded
    __shared__ float Ws[32][64];   // W tile [k][col]
    const int tid = threadIdx.x;
    const int tx = tid & 15, ty = tid >> 4;
    const int row0 = blockIdx.y * 64, col0 = blockIdx.x * 64;
    float acc[4][4] = {};

    for (int k0 = 0; k0 < K; k0 += 32) {
        // A tile: 64 rows x 32 cols, load float4, store transposed
#pragma unroll
        for (int t = 0; t < 2; ++t) {
            int idx = tid + t * 256;          // 0..511 float4 slots
            int r = idx >> 3;                 // 0..63
            int c4 = (idx & 7) * 4;           // 0..28
            float4 v = *reinterpret_cast<const float4*>(&A[(size_t)(row0 + r) * K + k0 + c4]);
            Ast[c4 + 0][r] = v.x; Ast[c4 + 1][r] = v.y;
            Ast[c4 + 2][r] = v.z; Ast[c4 + 3][r] = v.w;
        }
        // W tile: 32 rows x 64 cols
#pragma unroll
        for (int t = 0; t < 2; ++t) {
            int idx = tid + t * 256;
            int r = idx >> 4;                 // 0..31
            int c4 = (idx & 15) * 4;          // 0..60
            *reinterpret_cast<float4*>(&Ws[r][c4]) =
                *reinterpret_cast<const float4*>(&W[(size_t)(k0 + r) * N + col0 + c4]);
        }
        __syncthreads();
#pragma unroll
        for (int k = 0; k < 32; ++k) {
            float4 a = *reinterpret_cast<const float4*>(&Ast[k][ty * 4]);
            float4 b = *reinterpret_cast<const float4*>(&Ws[k][tx * 4]);
            float av[4] = {a.x, a.y, a.z, a.w};
            float bv[4] = {b.x, b.y, b.z, b.w};
#pragma unroll
            for (int i = 0; i < 4; ++i)
#pragma unroll
                for (int j = 0; j < 4; ++j) acc[i][j] = fmaf(av[i], bv[j], acc[i][j]);
        }
        __syncthreads();
    }
#pragma unroll
    for (int i = 0; i < 4; ++i) {
        int r = row0 + ty * 4 + i;
        int c = col0 + tx * 4;
        float4 v = {acc[i][0], acc[i][1], acc[i][2], acc[i][3]};
        if (bias) { v.x += bias[c]; v.y += bias[c + 1]; v.z += bias[c + 2]; v.w += bias[c + 3]; }
        *reinterpret_cast<float4*>(&C[(size_t)r * N + c]) = v;
    }
}

// ---------------- GCN aggregation ----------------
// out[d][f] = relu( dinv[d]*sum_{e:dst=d} dinv[src]*xw[src][f] + dinv[d]^2*xw[d][f] + b[f] )

template <int F>
__global__ __launch_bounds__(256) void gcn_agg_kernel(const float* __restrict__ xw,
                                                      const float* __restrict__ dinv,
                                                      const int* __restrict__ off,
                                                      const int* __restrict__ csr_src,
                                                      const float* __restrict__ bias,
                                                      float* __restrict__ out) {
    constexpr int PER = 256 / F;
    int d = blockIdx.x * PER + threadIdx.x / F;
    int f = threadIdx.x & (F - 1);
    int beg = off[d], end = off[d + 1];
    float acc = 0.f;
    for (int e = beg; e < end; ++e) {
        int s = csr_src[e];
        acc += dinv[s] * xw[(size_t)s * F + f];
    }
    float dd = dinv[d];
    float v = fmaf(acc, dd, fmaf(dd * dd, xw[(size_t)d * F + f], bias[f]));
    out[(size_t)d * F + f] = fmaxf(v, 0.f);
}

// ---------------- reparameterization ----------------

__global__ __launch_bounds__(256) void z_kernel(const float* __restrict__ noise,
                                                const float* __restrict__ meanb,
                                                const float* __restrict__ logstd,
                                                float* __restrict__ z) {
    int i = blockIdx.x * 256 + threadIdx.x;
    z[i] = fmaf(noise[i], expf(logstd[i]), meanb[i]);
}

// ---------------- decoder: out = triu(sigmoid(z z^T), 1) ----------------
// 128x128 tile per block; 256 threads; 8x8 register blocking; K=64 single stage.

__global__ __launch_bounds__(256) void decode_kernel(const float* __restrict__ z,
                                                     float* __restrict__ out) {
    const int bi = blockIdx.y, bj = blockIdx.x;
    const int tid = threadIdx.x;

    if (bj < bi) {  // strictly-lower tile: all zeros
        const float4 zero = {0.f, 0.f, 0.f, 0.f};
        size_t base = (size_t)bi * 128 * N_NODES + (size_t)bj * 128;
        // 128x128 tile = 4096 float4 slots; 256 threads -> 16 iterations
#pragma unroll 4
        for (int t = 0; t < 16; ++t) {
            int slot = tid + t * 256;          // 0..4095
            int r = slot >> 5;                 // 0..127
            int c = (slot & 31) * 4;           // 0..124
            *reinterpret_cast<float4*>(&out[base + (size_t)r * N_NODES + c]) = zero;
        }
        return;
    }

    __shared__ float Zi[64][132];  // [k][row], padded for float4 reads
    __shared__ float Zj[64][132];
#pragma unroll
    for (int t = 0; t < 8; ++t) {
        int slot = tid + t * 256;   // 0..2047
        int r = slot >> 4;          // 0..127
        int c4 = (slot & 15) * 4;   // 0..60
        float4 vi = *reinterpret_cast<const float4*>(&z[(size_t)(bi * 128 + r) * OUTD + c4]);
        Zi[c4 + 0][r] = vi.x; Zi[c4 + 1][r] = vi.y; Zi[c4 + 2][r] = vi.z; Zi[c4 + 3][r] = vi.w;
        float4 vj = *reinterpret_cast<const float4*>(&z[(size_t)(bj * 128 + r) * OUTD + c4]);
        Zj[c4 + 0][r] = vj.x; Zj[c4 + 1][r] = vj.y; Zj[c4 + 2][r] = vj.z; Zj[c4 + 3][r] = vj.w;
    }
    __syncthreads();

    const int tx = tid & 15, ty = tid >> 4;
    float acc[8][8] = {};
#pragma unroll 8
    for (int k = 0; k < 64; ++k) {
        float4 a0 = *reinterpret_cast<const float4*>(&Zi[k][ty * 8]);
        float4 a1 = *reinterpret_cast<const float4*>(&Zi[k][ty * 8 + 4]);
        float4 b0 = *reinterpret_cast<const float4*>(&Zj[k][tx * 8]);
        float4 b1 = *reinterpret_cast<const float4*>(&Zj[k][tx * 8 + 4]);
        float av[8] = {a0.x, a0.y, a0.z, a0.w, a1.x, a1.y, a1.z, a1.w};
        float bv[8] = {b0.x, b0.y, b0.z, b0.w, b1.x, b1.y, b1.z, b1.w};
#pragma unroll
        for (int i = 0; i < 8; ++i)
#pragma unroll
            for (int j = 0; j < 8; ++j) acc[i][j] = fmaf(av[i], bv[j], acc[i][j]);
    }

    const bool diag = (bi == bj);
#pragma unroll
    for (int i = 0; i < 8; ++i) {
        int gi = bi * 128 + ty * 8 + i;
        size_t rowbase = (size_t)gi * N_NODES + (size_t)bj * 128 + tx * 8;
        float vals[8];
#pragma unroll
        for (int j = 0; j < 8; ++j) {
            int gj = bj * 128 + tx * 8 + j;
            float s = 1.f / (1.f + __expf(-acc[i][j]));
            if (diag && gj <= gi) s = 0.f;
            vals[j] = s;
        }
        *reinterpret_cast<float4*>(&out[rowbase])     = *reinterpret_cast<float4*>(&vals[0]);
        *reinterpret_cast<float4*>(&out[rowbase + 4]) = *reinterpret_cast<float4*>(&vals[4]);
    }
}

// ---------------- launch ----------------

extern "C" void kernel_launch(void* const* d_in, const int* in_sizes, int n_in,
                              void* d_out, int out_size, void* d_ws, size_t ws_size,
                              hipStream_t stream) {
    const float* x        = (const float*)d_in[0];
    const int*   ei       = (const int*)d_in[1];
    const float* noise    = (const float*)d_in[2];
    const float* mlp_w    = (const float*)d_in[3];
    const float* mlp_b    = (const float*)d_in[4];
    const float* w1       = (const float*)d_in[5];
    const float* b1       = (const float*)d_in[6];
    const float* w2       = (const float*)d_in[7];
    const float* b2       = (const float*)d_in[8];
    const float* w_mean   = (const float*)d_in[9];
    const float* b_mean   = (const float*)d_in[10];
    const float* w_logstd = (const float*)d_in[11];
    const float* b_logstd = (const float*)d_in[12];
    float* out = (float*)d_out;

    // ---- scratch layout ----
    // All pre-decode intermediates live in d_out (268 MB; fully overwritten by
    // decode_kernel at the end). Only z (read DURING decode) lives in d_ws.
    float* bufA   = out;                                   // 8192*256
    float* bufB   = bufA + (size_t)N_NODES * DIM;          // 8192*256
    float* bufC   = bufB + (size_t)N_NODES * DIM;          // 8192*256
    float* meanb  = bufC + (size_t)N_NODES * DIM;          // 8192*64
    float* logstd = meanb + (size_t)N_NODES * OUTD;        // 8192*64
    float* dinv   = logstd + (size_t)N_NODES * OUTD;       // 8192
    int* cnt     = (int*)(dinv + N_NODES);                 // 8192
    int* cursor  = cnt + N_NODES;                          // 8192
    int* off     = cursor + N_NODES;                       // 8704 (8193 used)
    int* csr_src = off + 8704;                             // 262144
    float* zb = (float*)d_ws;                              // 8192*64 = 2 MB

    const int* srcI = ei;
    const int* dstI = ei + N_EDGES;

    hipMemsetAsync(cnt, 0, 2 * N_NODES * sizeof(int), stream);  // cnt + cursor
    hist_kernel<<<N_EDGES / 256, 256, 0, stream>>>(dstI, cnt);
    dinv_kernel<<<N_NODES / 256, 256, 0, stream>>>(cnt, dinv);
    scan_kernel<<<1, 256, 0, stream>>>(cnt, off);
    fill_kernel<<<N_EDGES / 256, 256, 0, stream>>>(srcI, dstI, off, cursor, csr_src);

    dim3 g256(DIM / 64, N_NODES / 64);
    dim3 g64(OUTD / 64, N_NODES / 64);

    // h0 = x @ mlp_w + mlp_b
    gemm_f32<<<g256, 256, 0, stream>>>(x, mlp_w, mlp_b, bufA, N_NODES, DIM, DIM);
    // layer 1
    gemm_f32<<<g256, 256, 0, stream>>>(bufA, w1, nullptr, bufB, N_NODES, DIM, DIM);
    gcn_agg_kernel<256><<<N_NODES, 256, 0, stream>>>(bufB, dinv, off, csr_src, b1, bufC);
    // layer 2 (reuse bufA as output; bufB is the GEMM scratch)
    gemm_f32<<<g256, 256, 0, stream>>>(bufC, w2, nullptr, bufB, N_NODES, DIM, DIM);
    gcn_agg_kernel<256><<<N_NODES, 256, 0, stream>>>(bufB, dinv, off, csr_src, b2, bufA);
    // mean head
    gemm_f32<<<g64, 256, 0, stream>>>(bufA, w_mean, nullptr, bufB, N_NODES, OUTD, DIM);
    gcn_agg_kernel<64><<<N_NODES / 4, 256, 0, stream>>>(bufB, dinv, off, csr_src, b_mean, meanb);
    // logstd head
    gemm_f32<<<g64, 256, 0, stream>>>(bufA, w_logstd, nullptr, bufB, N_NODES, OUTD, DIM);
    gcn_agg_kernel<64><<<N_NODES / 4, 256, 0, stream>>>(bufB, dinv, off, csr_src, b_logstd, logstd);
    // z = noise * exp(logstd) + mean  (zb lives in d_ws, survives into decode)
    z_kernel<<<(N_NODES * OUTD) / 256, 256, 0, stream>>>(noise, meanb, logstd, zb);
    // decode: overwrites ALL of d_out
    dim3 gd(N_NODES / 128, N_NODES / 128);
    decode_kernel<<<gd, 256, 0, stream>>>(zb, out);
}

// Round 3
// 357.388 us; speedup vs baseline: 1.2349x; 1.2349x over previous
//
#include <hip/hip_runtime.h>
#include <math.h>

#define N_NODES 8192
#define N_EDGES 262144
#define DIM 256
#define OUTD 64

typedef __bf16 bf16x8 __attribute__((ext_vector_type(8)));
typedef float f32x4 __attribute__((ext_vector_type(4)));

// ---------------- CSR build ----------------

__global__ __launch_bounds__(256) void hist_kernel(const int* __restrict__ dst,
                                                   int* __restrict__ cnt) {
    int e = blockIdx.x * 256 + threadIdx.x;
    if (e < N_EDGES) atomicAdd(&cnt[dst[e]], 1);
}

// single-block exclusive scan of cnt[8192] -> off[0..8192]; also dinv = rsqrt(cnt+1)
__global__ __launch_bounds__(256) void scan_dinv_kernel(const int* __restrict__ cnt,
                                                        int* __restrict__ off,
                                                        float* __restrict__ dinv) {
    __shared__ int sums[256];
    int tid = threadIdx.x;
    int base = tid * 32;
    int local[32];
    int s = 0;
#pragma unroll
    for (int i = 0; i < 32; ++i) {
        int c = cnt[base + i];
        local[i] = s; s += c;
        dinv[base + i] = rsqrtf((float)(c + 1));  // +1 self-loop
    }
    sums[tid] = s;
    __syncthreads();
    for (int d = 1; d < 256; d <<= 1) {
        int v = (tid >= d) ? sums[tid - d] : 0;
        __syncthreads();
        sums[tid] += v;
        __syncthreads();
    }
    int pre = (tid == 0) ? 0 : sums[tid - 1];
#pragma unroll
    for (int i = 0; i < 32; ++i) off[base + i] = pre + local[i];
    if (tid == 255) off[N_NODES] = pre + s;
}

__global__ __launch_bounds__(256) void fill_kernel(const int* __restrict__ src,
                                                   const int* __restrict__ dst,
                                                   const int* __restrict__ off,
                                                   int* __restrict__ cursor,
                                                   int* __restrict__ csr_src) {
    int e = blockIdx.x * 256 + threadIdx.x;
    if (e < N_EDGES) {
        int d = dst[e];
        int p = atomicAdd(&cursor[d], 1);
        csr_src[off[d] + p] = src[e];
    }
}

// ---------------- dense GEMM: C[M,N] = A[M,K] @ W[K,N] (+ bias) ----------------

__global__ __launch_bounds__(256) void gemm_f32(const float* __restrict__ A,
                                                const float* __restrict__ W,
                                                const float* __restrict__ bias,
                                                float* __restrict__ C,
                                                int M, int N, int K) {
    __shared__ float Ast[32][68];  // transposed A tile [k][row], padded
    __shared__ float Ws[32][64];   // W tile [k][col]
    const int tid = threadIdx.x;
    const int tx = tid & 15, ty = tid >> 4;
    const int row0 = blockIdx.y * 64, col0 = blockIdx.x * 64;
    float acc[4][4] = {};

    for (int k0 = 0; k0 < K; k0 += 32) {
#pragma unroll
        for (int t = 0; t < 2; ++t) {
            int idx = tid + t * 256;
            int r = idx >> 3;
            int c4 = (idx & 7) * 4;
            float4 v = *reinterpret_cast<const float4*>(&A[(size_t)(row0 + r) * K + k0 + c4]);
            Ast[c4 + 0][r] = v.x; Ast[c4 + 1][r] = v.y;
            Ast[c4 + 2][r] = v.z; Ast[c4 + 3][r] = v.w;
        }
#pragma unroll
        for (int t = 0; t < 2; ++t) {
            int idx = tid + t * 256;
            int r = idx >> 4;
            int c4 = (idx & 15) * 4;
            *reinterpret_cast<float4*>(&Ws[r][c4]) =
                *reinterpret_cast<const float4*>(&W[(size_t)(k0 + r) * N + col0 + c4]);
        }
        __syncthreads();
#pragma unroll
        for (int k = 0; k < 32; ++k) {
            float4 a = *reinterpret_cast<const float4*>(&Ast[k][ty * 4]);
            float4 b = *reinterpret_cast<const float4*>(&Ws[k][tx * 4]);
            float av[4] = {a.x, a.y, a.z, a.w};
            float bv[4] = {b.x, b.y, b.z, b.w};
#pragma unroll
            for (int i = 0; i < 4; ++i)
#pragma unroll
                for (int j = 0; j < 4; ++j) acc[i][j] = fmaf(av[i], bv[j], acc[i][j]);
        }
        __syncthreads();
    }
#pragma unroll
    for (int i = 0; i < 4; ++i) {
        int r = row0 + ty * 4 + i;
        int c = col0 + tx * 4;
        float4 v = {acc[i][0], acc[i][1], acc[i][2], acc[i][3]};
        if (bias) { v.x += bias[c]; v.y += bias[c + 1]; v.z += bias[c + 2]; v.w += bias[c + 3]; }
        *reinterpret_cast<float4*>(&C[(size_t)r * N + c]) = v;
    }
}

// ---------------- GCN aggregation (F=256): one dst per block ----------------

__global__ __launch_bounds__(256) void gcn_agg256_kernel(const float* __restrict__ xw,
                                                         const float* __restrict__ dinv,
                                                         const int* __restrict__ off,
                                                         const int* __restrict__ csr_src,
                                                         const float* __restrict__ bias,
                                                         float* __restrict__ out) {
    int d = blockIdx.x;
    int f = threadIdx.x;
    int beg = off[d], end = off[d + 1];
    float acc = 0.f;
    for (int e = beg; e < end; ++e) {
        int s = csr_src[e];
        acc += dinv[s] * xw[(size_t)s * DIM + f];
    }
    float dd = dinv[d];
    float v = fmaf(acc, dd, fmaf(dd * dd, xw[(size_t)d * DIM + f], bias[f]));
    out[(size_t)d * DIM + f] = fmaxf(v, 0.f);
}

// ---------------- fused head: agg(mean) + agg(logstd) + reparam + bf16 split ----------------
// 2 dst nodes per block. threads: half = t>>7 (dst), head = (t>>6)&1, f = t&63.

__global__ __launch_bounds__(256) void head_kernel(const float* __restrict__ xwm,
                                                   const float* __restrict__ xwl,
                                                   const float* __restrict__ dinv,
                                                   const int* __restrict__ off,
                                                   const int* __restrict__ csr_src,
                                                   const float* __restrict__ b_mean,
                                                   const float* __restrict__ b_logstd,
                                                   const float* __restrict__ noise,
                                                   unsigned short* __restrict__ zhi,
                                                   unsigned short* __restrict__ zlo) {
    const int tid = threadIdx.x;
    const int half = tid >> 7;
    const int d = blockIdx.x * 2 + half;
    const int head = (tid >> 6) & 1;
    const int f = tid & 63;
    const float* xw = head ? xwl : xwm;
    const float bias = head ? b_logstd[f] : b_mean[f];

    int beg = off[d], end = off[d + 1];
    float acc = 0.f;
    for (int e = beg; e < end; ++e) {
        int s = csr_src[e];
        acc += dinv[s] * xw[(size_t)s * OUTD + f];
    }
    float dd = dinv[d];
    float v = fmaf(acc, dd, fmaf(dd * dd, xw[(size_t)d * OUTD + f], bias));
    v = fmaxf(v, 0.f);

    __shared__ float sh[2][2][64];
    sh[half][head][f] = v;
    __syncthreads();

    if (head == 0) {
        float ls = sh[half][1][f];
        float z = fmaf(noise[(size_t)d * OUTD + f], expf(ls), v);
        // split z = hi + lo, both bf16 (rne)
        unsigned u = __float_as_uint(z);
        unsigned hi = (u + 0x7FFFu + ((u >> 16) & 1u)) >> 16;
        float fhi = __uint_as_float(hi << 16);
        float lo = z - fhi;
        unsigned ul = __float_as_uint(lo);
        unsigned hl = (ul + 0x7FFFu + ((ul >> 16) & 1u)) >> 16;
        zhi[(size_t)d * OUTD + f] = (unsigned short)hi;
        zlo[(size_t)d * OUTD + f] = (unsigned short)hl;
    }
}

// ---------------- decoder: out = triu(sigmoid(z z^T), 1), split-bf16 MFMA ----------------
// 128x128 tile, 4 waves; wave w handles rows w*32..w*32+31 (2 mtiles) x 128 cols (8 ntiles).
// K=64 = 2 ktiles of 32. 3 MFMAs per (m,n,kt): hi*hi + hi*lo + lo*hi.

__global__ __launch_bounds__(256) void decode_mfma_kernel(const unsigned short* __restrict__ zhi,
                                                          const unsigned short* __restrict__ zlo,
                                                          float* __restrict__ out) {
    const int bi = blockIdx.y, bj = blockIdx.x;
    const int tid = threadIdx.x;

    if (bj < bi) {  // strictly-lower tile: all zeros (16384 floats = 4096 float4)
        const float4 zero = {0.f, 0.f, 0.f, 0.f};
        size_t base = (size_t)bi * 128 * N_NODES + (size_t)bj * 128;
#pragma unroll 4
        for (int t = 0; t < 16; ++t) {
            int slot = tid + t * 256;
            int r = slot >> 5;
            int c = (slot & 31) * 4;
            *reinterpret_cast<float4*>(&out[base + (size_t)r * N_NODES + c]) = zero;
        }
        return;
    }

    __shared__ float sh[128][128];  // 64 KB transpose buffer

    const int lane = tid & 63;
    const int w = tid >> 6;          // wave 0..3
    const int lr = lane & 15;        // node row within 16-tile
    const int kq = lane >> 4;        // feature quad 0..3

    const f32x4 zero4 = {0.f, 0.f, 0.f, 0.f};
    f32x4 acc[2][8];
#pragma unroll
    for (int m = 0; m < 2; ++m)
#pragma unroll
        for (int n = 0; n < 8; ++n) acc[m][n] = zero4;

    // A fragments: Zi rows bi*128 + w*32 + m*16 + lr, feats kt*32 + kq*8 .. +8
    bf16x8 ah[2][2], al[2][2];
#pragma unroll
    for (int m = 0; m < 2; ++m)
#pragma unroll
        for (int kt = 0; kt < 2; ++kt) {
            size_t idx = (size_t)(bi * 128 + w * 32 + m * 16 + lr) * OUTD + kt * 32 + kq * 8;
            ah[m][kt] = *reinterpret_cast<const bf16x8*>(&zhi[idx]);
            al[m][kt] = *reinterpret_cast<const bf16x8*>(&zlo[idx]);
        }

#pragma unroll
    for (int n = 0; n < 8; ++n) {
        bf16x8 bh[2], bl[2];
#pragma unroll
        for (int kt = 0; kt < 2; ++kt) {
            size_t idx = (size_t)(bj * 128 + n * 16 + lr) * OUTD + kt * 32 + kq * 8;
            bh[kt] = *reinterpret_cast<const bf16x8*>(&zhi[idx]);
            bl[kt] = *reinterpret_cast<const bf16x8*>(&zlo[idx]);
        }
#pragma unroll
        for (int m = 0; m < 2; ++m)
#pragma unroll
            for (int kt = 0; kt < 2; ++kt) {
                acc[m][n] = __builtin_amdgcn_mfma_f32_16x16x32_bf16(ah[m][kt], bh[kt], acc[m][n], 0, 0, 0);
                acc[m][n] = __builtin_amdgcn_mfma_f32_16x16x32_bf16(ah[m][kt], bl[kt], acc[m][n], 0, 0, 0);
                acc[m][n] = __builtin_amdgcn_mfma_f32_16x16x32_bf16(al[m][kt], bh[kt], acc[m][n], 0, 0, 0);
            }
    }

    // D layout: row = kq*4 + r, col = lr  (verified m89 mapping)
#pragma unroll
    for (int m = 0; m < 2; ++m)
#pragma unroll
        for (int n = 0; n < 8; ++n)
#pragma unroll
            for (int r = 0; r < 4; ++r)
                sh[w * 32 + m * 16 + kq * 4 + r][n * 16 + lr] = acc[m][n][r];
    __syncthreads();

    // epilogue: coalesced float4 rows, sigmoid, triu mask on diag blocks
    const bool diag = (bi == bj);
#pragma unroll
    for (int it = 0; it < 16; ++it) {
        int row = it * 8 + (tid >> 5);
        int col = (tid & 31) * 4;
        float4 v = *reinterpret_cast<const float4*>(&sh[row][col]);
        int gi = bi * 128 + row;
        int gj = bj * 128 + col;
        float vals[4] = {v.x, v.y, v.z, v.w};
#pragma unroll
        for (int j = 0; j < 4; ++j) {
            float s = 1.f / (1.f + __expf(-vals[j]));
            if (diag && (gj + j) <= gi) s = 0.f;
            vals[j] = s;
        }
        float4 o = {vals[0], vals[1], vals[2], vals[3]};
        *reinterpret_cast<float4*>(&out[(size_t)gi * N_NODES + gj]) = o;
    }
}

// ---------------- launch ----------------

extern "C" void kernel_launch(void* const* d_in, const int* in_sizes, int n_in,
                              void* d_out, int out_size, void* d_ws, size_t ws_size,
                              hipStream_t stream) {
    const float* x        = (const float*)d_in[0];
    const int*   ei       = (const int*)d_in[1];
    const float* noise    = (const float*)d_in[2];
    const float* mlp_w    = (const float*)d_in[3];
    const float* mlp_b    = (const float*)d_in[4];
    const float* w1       = (const float*)d_in[5];
    const float* b1       = (const float*)d_in[6];
    const float* w2       = (const float*)d_in[7];
    const float* b2       = (const float*)d_in[8];
    const float* w_mean   = (const float*)d_in[9];
    const float* b_mean   = (const float*)d_in[10];
    const float* w_logstd = (const float*)d_in[11];
    const float* b_logstd = (const float*)d_in[12];
    float* out = (float*)d_out;

    // pre-decode intermediates live in d_out (fully overwritten by decode);
    // only zhi/zlo (read during decode) live in d_ws.
    float* bufA   = out;                                   // 8192*256
    float* bufB   = bufA + (size_t)N_NODES * DIM;          // 8192*256 (xw scratch)
    float* bufC   = bufB + (size_t)N_NODES * DIM;          // 8192*256
    float* xwm    = bufB;                                  // head gemm outputs (8192*64)
    float* xwl    = bufB + (size_t)N_NODES * OUTD;
    float* dinv   = bufC + (size_t)N_NODES * DIM;          // 8192
    int* cnt     = (int*)(dinv + N_NODES);                 // 8192
    int* cursor  = cnt + N_NODES;                          // 8192
    int* off     = cursor + N_NODES;                       // 8193 (pad to 8704)
    int* csr_src = off + 8704;                             // 262144
    unsigned short* zhi = (unsigned short*)d_ws;           // 8192*64
    unsigned short* zlo = zhi + (size_t)N_NODES * OUTD;    // 8192*64

    const int* srcI = ei;
    const int* dstI = ei + N_EDGES;

    hipMemsetAsync(cnt, 0, 2 * N_NODES * sizeof(int), stream);  // cnt + cursor
    hist_kernel<<<N_EDGES / 256, 256, 0, stream>>>(dstI, cnt);
    scan_dinv_kernel<<<1, 256, 0, stream>>>(cnt, off, dinv);
    fill_kernel<<<N_EDGES / 256, 256, 0, stream>>>(srcI, dstI, off, cursor, csr_src);

    dim3 g256(DIM / 64, N_NODES / 64);
    dim3 g64(OUTD / 64, N_NODES / 64);

    // h0 = x @ mlp_w + mlp_b
    gemm_f32<<<g256, 256, 0, stream>>>(x, mlp_w, mlp_b, bufA, N_NODES, DIM, DIM);
    // layer 1
    gemm_f32<<<g256, 256, 0, stream>>>(bufA, w1, nullptr, bufB, N_NODES, DIM, DIM);
    gcn_agg256_kernel<<<N_NODES, 256, 0, stream>>>(bufB, dinv, off, csr_src, b1, bufC);
    // layer 2
    gemm_f32<<<g256, 256, 0, stream>>>(bufC, w2, nullptr, bufB, N_NODES, DIM, DIM);
    gcn_agg256_kernel<<<N_NODES, 256, 0, stream>>>(bufB, dinv, off, csr_src, b2, bufA);
    // heads: two small gemms, then fused agg+reparam+split
    gemm_f32<<<g64, 256, 0, stream>>>(bufA, w_mean,   nullptr, xwm, N_NODES, OUTD, DIM);
    gemm_f32<<<g64, 256, 0, stream>>>(bufA, w_logstd, nullptr, xwl, N_NODES, OUTD, DIM);
    head_kernel<<<N_NODES / 2, 256, 0, stream>>>(xwm, xwl, dinv, off, csr_src,
                                                 b_mean, b_logstd, noise, zhi, zlo);
    // decode: overwrites ALL of d_out
    dim3 gd(N_NODES / 128, N_NODES / 128);
    decode_mfma_kernel<<<gd, 256, 0, stream>>>(zhi, zlo, out);
}

// Round 4
// 277.049 us; speedup vs baseline: 1.5930x; 1.2900x over previous
//
#include <hip/hip_runtime.h>
#include <math.h>

#define N_NODES 8192
#define N_EDGES 262144
#define DIM 256
#define OUTD 64

typedef __bf16 bf16x8 __attribute__((ext_vector_type(8)));
typedef float f32x4 __attribute__((ext_vector_type(4)));
typedef unsigned short u16;
typedef u16 u16x4 __attribute__((ext_vector_type(4)));
typedef u16 u16x8 __attribute__((ext_vector_type(8)));

union BC8 { u16x8 u; bf16x8 b; };

// round-to-nearest-even split: x = hi + lo, both bf16
__device__ inline void bsplit(float x, u16& h, u16& l) {
    unsigned u = __float_as_uint(x);
    unsigned hi = (u + 0x7FFFu + ((u >> 16) & 1u)) >> 16;
    float fhi = __uint_as_float(hi << 16);
    float lo = x - fhi;
    unsigned ul = __float_as_uint(lo);
    h = (u16)hi;
    l = (u16)((ul + 0x7FFFu + ((ul >> 16) & 1u)) >> 16);
}

// ---------------- CSR build ----------------

__global__ __launch_bounds__(256) void hist_kernel(const int* __restrict__ dst,
                                                   int* __restrict__ cnt) {
    int e = blockIdx.x * 256 + threadIdx.x;
    if (e < N_EDGES) atomicAdd(&cnt[dst[e]], 1);
}

__global__ __launch_bounds__(256) void scan_dinv_kernel(const int* __restrict__ cnt,
                                                        int* __restrict__ off,
                                                        float* __restrict__ dinv) {
    __shared__ int sums[256];
    int tid = threadIdx.x;
    int base = tid * 32;
    int local[32];
    int s = 0;
#pragma unroll
    for (int i = 0; i < 32; ++i) {
        int c = cnt[base + i];
        local[i] = s; s += c;
        dinv[base + i] = rsqrtf((float)(c + 1));
    }
    sums[tid] = s;
    __syncthreads();
    for (int d = 1; d < 256; d <<= 1) {
        int v = (tid >= d) ? sums[tid - d] : 0;
        __syncthreads();
        sums[tid] += v;
        __syncthreads();
    }
    int pre = (tid == 0) ? 0 : sums[tid - 1];
#pragma unroll
    for (int i = 0; i < 32; ++i) off[base + i] = pre + local[i];
    if (tid == 255) off[N_NODES] = pre + s;
}

__global__ __launch_bounds__(256) void fill_kernel(const int* __restrict__ src,
                                                   const int* __restrict__ dst,
                                                   const int* __restrict__ off,
                                                   int* __restrict__ cursor,
                                                   int* __restrict__ csr_src) {
    int e = blockIdx.x * 256 + threadIdx.x;
    if (e < N_EDGES) {
        int d = dst[e];
        int p = atomicAdd(&cursor[d], 1);
        csr_src[off[d] + p] = src[e];
    }
}

// ---------------- weight transpose + split: Wt_hi/lo[n][k] = bf16split(W[k][n]) ----------------
// blockIdx.z selects which weight; 64x64 tile per block.

__global__ __launch_bounds__(256) void wsplit_kernel(const float* __restrict__ mlp_w,
                                                     const float* __restrict__ w1,
                                                     const float* __restrict__ w2,
                                                     const float* __restrict__ wm,
                                                     const float* __restrict__ wl,
                                                     u16* __restrict__ wtm_hi, u16* __restrict__ wtm_lo,
                                                     u16* __restrict__ wt1_hi, u16* __restrict__ wt1_lo,
                                                     u16* __restrict__ wt2_hi, u16* __restrict__ wt2_lo,
                                                     u16* __restrict__ wth_hi, u16* __restrict__ wth_lo) {
    const int z = blockIdx.z;
    const float* W; u16 *hi, *lo; int N, rowoff;
    if (z == 0)      { W = mlp_w; hi = wtm_hi; lo = wtm_lo; N = 256; rowoff = 0; }
    else if (z == 1) { W = w1;    hi = wt1_hi; lo = wt1_lo; N = 256; rowoff = 0; }
    else if (z == 2) { W = w2;    hi = wt2_hi; lo = wt2_lo; N = 256; rowoff = 0; }
    else if (z == 3) { W = wm;    hi = wth_hi; lo = wth_lo; N = 64;  rowoff = 0; }
    else             { W = wl;    hi = wth_hi; lo = wth_lo; N = 64;  rowoff = 64; }
    if (blockIdx.x * 64 >= N) return;

    const int k0 = blockIdx.y * 64, n0 = blockIdx.x * 64;
    const int tid = threadIdx.x;
    __shared__ float lds[64][68];
#pragma unroll
    for (int it = 0; it < 4; ++it) {
        int slot = tid + it * 256;        // 1024 float4 slots
        int r = slot >> 4;                // k 0..63
        int c4 = (slot & 15) * 4;         // n 0..60
        float4 v = *reinterpret_cast<const float4*>(&W[(size_t)(k0 + r) * N + n0 + c4]);
        lds[r][c4] = v.x; lds[r][c4 + 1] = v.y; lds[r][c4 + 2] = v.z; lds[r][c4 + 3] = v.w;
    }
    __syncthreads();
#pragma unroll
    for (int it = 0; it < 4; ++it) {
        int slot = tid + it * 256;
        int n = slot >> 4;                // 0..63
        int k4 = (slot & 15) * 4;         // 0..60
        u16x4 h4, l4;
#pragma unroll
        for (int j = 0; j < 4; ++j) {
            u16 h, l;
            bsplit(lds[k4 + j][n], h, l);
            h4[j] = h; l4[j] = l;
        }
        size_t o = (size_t)(rowoff + n0 + n) * 256 + k0 + k4;
        *reinterpret_cast<u16x4*>(&hi[o]) = h4;
        *reinterpret_cast<u16x4*>(&lo[o]) = l4;
    }
}

// ---------------- split x into hi/lo bf16 ----------------

__global__ __launch_bounds__(256) void split_x_kernel(const float* __restrict__ x,
                                                      u16* __restrict__ xhi,
                                                      u16* __restrict__ xlo) {
    int i = blockIdx.x * 256 + threadIdx.x;   // float4 index
    float4 v = *reinterpret_cast<const float4*>(&x[(size_t)i * 4]);
    float xs[4] = {v.x, v.y, v.z, v.w};
    u16x4 h4, l4;
#pragma unroll
    for (int j = 0; j < 4; ++j) { u16 h, l; bsplit(xs[j], h, l); h4[j] = h; l4[j] = l; }
    *reinterpret_cast<u16x4*>(&xhi[(size_t)i * 4]) = h4;
    *reinterpret_cast<u16x4*>(&xlo[(size_t)i * 4]) = l4;
}

// ---------------- split-bf16 MFMA GEMM ----------------
// C[M,N] = A[M,256] @ W[256,N]; A as hi/lo bf16 [M][256]; W as Wt hi/lo bf16 [N][256].
// Block: 4 waves; wave w owns rows (blockIdx.y*4 + w)*MT*16 .. +MT*16; cols col0..col0+NT*16.
// 3 MFMAs per (m,n,ktile): hi*hi + hi*lo + lo*hi.

template <int MT, int NT, bool OSPLIT>
__global__ __launch_bounds__(256) void gemm_mfma(const u16* __restrict__ Ahi,
                                                 const u16* __restrict__ Alo,
                                                 const u16* __restrict__ Bhi,
                                                 const u16* __restrict__ Blo,
                                                 const float* __restrict__ bias,
                                                 float* __restrict__ Cf,
                                                 u16* __restrict__ Chi,
                                                 u16* __restrict__ Clo,
                                                 int ldc) {
    const int tid = threadIdx.x;
    const int lane = tid & 63, w = tid >> 6;
    const int lr = lane & 15, kq = lane >> 4;
    const int row0 = (blockIdx.y * 4 + w) * (MT * 16);
    const int col0 = blockIdx.x * (NT * 16);

    f32x4 acc[MT][NT];
#pragma unroll
    for (int m = 0; m < MT; ++m)
#pragma unroll
        for (int n = 0; n < NT; ++n) acc[m][n] = (f32x4){0.f, 0.f, 0.f, 0.f};

#pragma unroll
    for (int kt = 0; kt < 8; ++kt) {
        const int k0 = kt * 32 + kq * 8;
        bf16x8 ah[MT], al[MT];
#pragma unroll
        for (int m = 0; m < MT; ++m) {
            size_t o = (size_t)(row0 + m * 16 + lr) * 256 + k0;
            ah[m] = *reinterpret_cast<const bf16x8*>(&Ahi[o]);
            al[m] = *reinterpret_cast<const bf16x8*>(&Alo[o]);
        }
        bf16x8 bh[NT], bl[NT];
#pragma unroll
        for (int n = 0; n < NT; ++n) {
            size_t o = (size_t)(col0 + n * 16 + lr) * 256 + k0;
            bh[n] = *reinterpret_cast<const bf16x8*>(&Bhi[o]);
            bl[n] = *reinterpret_cast<const bf16x8*>(&Blo[o]);
        }
#pragma unroll
        for (int m = 0; m < MT; ++m)
#pragma unroll
            for (int n = 0; n < NT; ++n) {
                acc[m][n] = __builtin_amdgcn_mfma_f32_16x16x32_bf16(ah[m], bh[n], acc[m][n], 0, 0, 0);
                acc[m][n] = __builtin_amdgcn_mfma_f32_16x16x32_bf16(ah[m], bl[n], acc[m][n], 0, 0, 0);
                acc[m][n] = __builtin_amdgcn_mfma_f32_16x16x32_bf16(al[m], bh[n], acc[m][n], 0, 0, 0);
            }
    }

    // C/D layout: col = lr, row = kq*4 + r (m89-verified)
#pragma unroll
    for (int m = 0; m < MT; ++m)
#pragma unroll
        for (int n = 0; n < NT; ++n) {
            int col = col0 + n * 16 + lr;
            float b = bias ? bias[col] : 0.f;
#pragma unroll
            for (int r = 0; r < 4; ++r) {
                int row = row0 + m * 16 + kq * 4 + r;
                float v = acc[m][n][r] + b;
                size_t o = (size_t)row * ldc + col;
                if (OSPLIT) {
                    u16 h, l; bsplit(v, h, l);
                    Chi[o] = h; Clo[o] = l;
                } else {
                    Cf[o] = v;
                }
            }
        }
}

// ---------------- GCN aggregation (F=256), relu + bias, split-bf16 output ----------------

__global__ __launch_bounds__(256) void gcn_agg_kernel(const float* __restrict__ xw,
                                                      const float* __restrict__ dinv,
                                                      const int* __restrict__ off,
                                                      const int* __restrict__ csr_src,
                                                      const float* __restrict__ bias,
                                                      u16* __restrict__ ohi,
                                                      u16* __restrict__ olo) {
    int d = blockIdx.x;
    int f = threadIdx.x;
    int beg = off[d], end = off[d + 1];
    float acc = 0.f;
    int e = beg;
    for (; e + 3 < end; e += 4) {
        int s0 = csr_src[e], s1 = csr_src[e + 1], s2 = csr_src[e + 2], s3 = csr_src[e + 3];
        float w0 = dinv[s0], w1 = dinv[s1], w2 = dinv[s2], w3 = dinv[s3];
        float v0 = xw[(size_t)s0 * DIM + f];
        float v1 = xw[(size_t)s1 * DIM + f];
        float v2 = xw[(size_t)s2 * DIM + f];
        float v3 = xw[(size_t)s3 * DIM + f];
        acc += w0 * v0 + w1 * v1 + w2 * v2 + w3 * v3;
    }
    for (; e < end; ++e) {
        int s = csr_src[e];
        acc += dinv[s] * xw[(size_t)s * DIM + f];
    }
    float dd = dinv[d];
    float v = fmaf(acc, dd, fmaf(dd * dd, xw[(size_t)d * DIM + f], bias[f]));
    v = fmaxf(v, 0.f);
    u16 h, l; bsplit(v, h, l);
    ohi[(size_t)d * DIM + f] = h;
    olo[(size_t)d * DIM + f] = l;
}

// ---------------- fused head: agg(mean)+agg(logstd)+reparam+split ----------------
// xwcat is [N][128]: cols 0..63 = mean proj, 64..127 = logstd proj.

__global__ __launch_bounds__(256) void head_kernel(const float* __restrict__ xwcat,
                                                   const float* __restrict__ dinv,
                                                   const int* __restrict__ off,
                                                   const int* __restrict__ csr_src,
                                                   const float* __restrict__ b_mean,
                                                   const float* __restrict__ b_logstd,
                                                   const float* __restrict__ noise,
                                                   u16* __restrict__ zhi,
                                                   u16* __restrict__ zlo) {
    const int tid = threadIdx.x;
    const int half = tid >> 7;
    const int d = blockIdx.x * 2 + half;
    const int head = (tid >> 6) & 1;
    const int f = tid & 63;
    const int fc = head * 64 + f;
    const float bias = head ? b_logstd[f] : b_mean[f];

    int beg = off[d], end = off[d + 1];
    float acc = 0.f;
    int e = beg;
    for (; e + 3 < end; e += 4) {
        int s0 = csr_src[e], s1 = csr_src[e + 1], s2 = csr_src[e + 2], s3 = csr_src[e + 3];
        float w0 = dinv[s0], w1 = dinv[s1], w2 = dinv[s2], w3 = dinv[s3];
        float v0 = xwcat[(size_t)s0 * 128 + fc];
        float v1 = xwcat[(size_t)s1 * 128 + fc];
        float v2 = xwcat[(size_t)s2 * 128 + fc];
        float v3 = xwcat[(size_t)s3 * 128 + fc];
        acc += w0 * v0 + w1 * v1 + w2 * v2 + w3 * v3;
    }
    for (; e < end; ++e) {
        int s = csr_src[e];
        acc += dinv[s] * xwcat[(size_t)s * 128 + fc];
    }
    float dd = dinv[d];
    float v = fmaf(acc, dd, fmaf(dd * dd, xwcat[(size_t)d * 128 + fc], bias));
    v = fmaxf(v, 0.f);

    __shared__ float sh[2][2][64];
    sh[half][head][f] = v;
    __syncthreads();

    if (head == 0) {
        float ls = sh[half][1][f];
        float z = fmaf(noise[(size_t)d * OUTD + f], expf(ls), v);
        u16 h, l; bsplit(z, h, l);
        zhi[(size_t)d * OUTD + f] = h;
        zlo[(size_t)d * OUTD + f] = l;
    }
}

// ---------------- decoder: out = triu(sigmoid(z z^T), 1), split-bf16 MFMA ----------------

__global__ __launch_bounds__(256) void decode_mfma_kernel(const u16* __restrict__ zhi,
                                                          const u16* __restrict__ zlo,
                                                          float* __restrict__ out) {
    const int bi = blockIdx.y, bj = blockIdx.x;
    const int tid = threadIdx.x;

    if (bj < bi) {
        const float4 zero = {0.f, 0.f, 0.f, 0.f};
        size_t base = (size_t)bi * 128 * N_NODES + (size_t)bj * 128;
#pragma unroll 4
        for (int t = 0; t < 16; ++t) {
            int slot = tid + t * 256;
            int r = slot >> 5;
            int c = (slot & 31) * 4;
            *reinterpret_cast<float4*>(&out[base + (size_t)r * N_NODES + c]) = zero;
        }
        return;
    }

    __shared__ float sh[128][128];

    const int lane = tid & 63;
    const int w = tid >> 6;
    const int lr = lane & 15;
    const int kq = lane >> 4;

    f32x4 acc[2][8];
#pragma unroll
    for (int m = 0; m < 2; ++m)
#pragma unroll
        for (int n = 0; n < 8; ++n) acc[m][n] = (f32x4){0.f, 0.f, 0.f, 0.f};

    bf16x8 ah[2][2], al[2][2];
#pragma unroll
    for (int m = 0; m < 2; ++m)
#pragma unroll
        for (int kt = 0; kt < 2; ++kt) {
            size_t idx = (size_t)(bi * 128 + w * 32 + m * 16 + lr) * OUTD + kt * 32 + kq * 8;
            ah[m][kt] = *reinterpret_cast<const bf16x8*>(&zhi[idx]);
            al[m][kt] = *reinterpret_cast<const bf16x8*>(&zlo[idx]);
        }

#pragma unroll
    for (int n = 0; n < 8; ++n) {
        bf16x8 bh[2], bl[2];
#pragma unroll
        for (int kt = 0; kt < 2; ++kt) {
            size_t idx = (size_t)(bj * 128 + n * 16 + lr) * OUTD + kt * 32 + kq * 8;
            bh[kt] = *reinterpret_cast<const bf16x8*>(&zhi[idx]);
            bl[kt] = *reinterpret_cast<const bf16x8*>(&zlo[idx]);
        }
#pragma unroll
        for (int m = 0; m < 2; ++m)
#pragma unroll
            for (int kt = 0; kt < 2; ++kt) {
                acc[m][n] = __builtin_amdgcn_mfma_f32_16x16x32_bf16(ah[m][kt], bh[kt], acc[m][n], 0, 0, 0);
                acc[m][n] = __builtin_amdgcn_mfma_f32_16x16x32_bf16(ah[m][kt], bl[kt], acc[m][n], 0, 0, 0);
                acc[m][n] = __builtin_amdgcn_mfma_f32_16x16x32_bf16(al[m][kt], bh[kt], acc[m][n], 0, 0, 0);
            }
    }

#pragma unroll
    for (int m = 0; m < 2; ++m)
#pragma unroll
        for (int n = 0; n < 8; ++n)
#pragma unroll
            for (int r = 0; r < 4; ++r)
                sh[w * 32 + m * 16 + kq * 4 + r][n * 16 + lr] = acc[m][n][r];
    __syncthreads();

    const bool diag = (bi == bj);
#pragma unroll
    for (int it = 0; it < 16; ++it) {
        int row = it * 8 + (tid >> 5);
        int col = (tid & 31) * 4;
        float4 v = *reinterpret_cast<const float4*>(&sh[row][col]);
        int gi = bi * 128 + row;
        int gj = bj * 128 + col;
        float vals[4] = {v.x, v.y, v.z, v.w};
#pragma unroll
        for (int j = 0; j < 4; ++j) {
            float s = 1.f / (1.f + __expf(-vals[j]));
            if (diag && (gj + j) <= gi) s = 0.f;
            vals[j] = s;
        }
        float4 o = {vals[0], vals[1], vals[2], vals[3]};
        *reinterpret_cast<float4*>(&out[(size_t)gi * N_NODES + gj]) = o;
    }
}

// ---------------- launch ----------------

extern "C" void kernel_launch(void* const* d_in, const int* in_sizes, int n_in,
                              void* d_out, int out_size, void* d_ws, size_t ws_size,
                              hipStream_t stream) {
    const float* x        = (const float*)d_in[0];
    const int*   ei       = (const int*)d_in[1];
    const float* noise    = (const float*)d_in[2];
    const float* mlp_w    = (const float*)d_in[3];
    const float* mlp_b    = (const float*)d_in[4];
    const float* w1       = (const float*)d_in[5];
    const float* b1       = (const float*)d_in[6];
    const float* w2       = (const float*)d_in[7];
    const float* b2       = (const float*)d_in[8];
    const float* w_mean   = (const float*)d_in[9];
    const float* b_mean   = (const float*)d_in[10];
    const float* w_logstd = (const float*)d_in[11];
    const float* b_logstd = (const float*)d_in[12];
    float* outf = (float*)d_out;

    // ---- scratch in d_out (fully overwritten by decode at the end) ----
    const size_t S = (size_t)N_NODES * DIM;            // 2,097,152
    u16* h0hi = (u16*)outf;                            // S u16
    u16* h0lo = h0hi + S;                              // [0, S) floats total
    float* xw = outf + S;                              // [S, 2S) f32 (xw1, then xw2)
    u16* h1hi = (u16*)(outf + 2 * S);
    u16* h1lo = h1hi + S;                              // [2S, 3S)
    u16* h2hi = h0hi;                                  // reuse h0 region
    u16* h2lo = h0lo;
    float* xwcat = outf + 3 * S;                       // [3S, 3.5S) f32 [8192][128]
    float* dinv = outf + 3 * S + S / 2;
    int* cnt     = (int*)(dinv + N_NODES);
    int* cursor  = cnt + N_NODES;
    int* off     = cursor + N_NODES;                   // 8193 used, pad 8704
    int* csr_src = off + 8704;
    u16* wt = (u16*)(outf + 4 * S);
    u16* wtm_hi = wt;               u16* wtm_lo = wt + 65536;
    u16* wt1_hi = wt + 131072;      u16* wt1_lo = wt + 196608;
    u16* wt2_hi = wt + 262144;      u16* wt2_lo = wt + 327680;
    u16* wth_hi = wt + 393216;      u16* wth_lo = wt + 425984;   // [128][256] each
    u16* xhi = (u16*)(outf + 5 * S);
    u16* xlo = xhi + S;                                // [5S, 6S)

    u16* zhi = (u16*)d_ws;                             // 8192*64
    u16* zlo = zhi + (size_t)N_NODES * OUTD;

    const int* srcI = ei;
    const int* dstI = ei + N_EDGES;

    hipMemsetAsync(cnt, 0, 2 * N_NODES * sizeof(int), stream);
    hist_kernel<<<N_EDGES / 256, 256, 0, stream>>>(dstI, cnt);
    scan_dinv_kernel<<<1, 256, 0, stream>>>(cnt, off, dinv);
    fill_kernel<<<N_EDGES / 256, 256, 0, stream>>>(srcI, dstI, off, cursor, csr_src);

    wsplit_kernel<<<dim3(4, 4, 5), 256, 0, stream>>>(mlp_w, w1, w2, w_mean, w_logstd,
                                                     wtm_hi, wtm_lo, wt1_hi, wt1_lo,
                                                     wt2_hi, wt2_lo, wth_hi, wth_lo);
    split_x_kernel<<<(N_NODES * DIM / 4) / 256, 256, 0, stream>>>(x, xhi, xlo);

    dim3 g256(4, 64);   // 64-col x 128-row tiles over [8192][256]
    // h0 = x @ mlp_w + mlp_b  (split out)
    gemm_mfma<2, 4, true><<<g256, 256, 0, stream>>>(xhi, xlo, wtm_hi, wtm_lo, mlp_b,
                                                    nullptr, h0hi, h0lo, DIM);
    // xw1 = h0 @ w1 (f32 out)
    gemm_mfma<2, 4, false><<<g256, 256, 0, stream>>>(h0hi, h0lo, wt1_hi, wt1_lo, nullptr,
                                                     xw, nullptr, nullptr, DIM);
    gcn_agg_kernel<<<N_NODES, 256, 0, stream>>>(xw, dinv, off, csr_src, b1, h1hi, h1lo);
    // xw2 = h1 @ w2
    gemm_mfma<2, 4, false><<<g256, 256, 0, stream>>>(h1hi, h1lo, wt2_hi, wt2_lo, nullptr,
                                                     xw, nullptr, nullptr, DIM);
    gcn_agg_kernel<<<N_NODES, 256, 0, stream>>>(xw, dinv, off, csr_src, b2, h2hi, h2lo);
    // xwcat = h2 @ [Wm | Wl]  (f32, [8192][128])
    gemm_mfma<1, 8, false><<<dim3(1, 128), 256, 0, stream>>>(h2hi, h2lo, wth_hi, wth_lo, nullptr,
                                                             xwcat, nullptr, nullptr, 128);
    head_kernel<<<N_NODES / 2, 256, 0, stream>>>(xwcat, dinv, off, csr_src,
                                                 b_mean, b_logstd, noise, zhi, zlo);
    dim3 gd(N_NODES / 128, N_NODES / 128);
    decode_mfma_kernel<<<gd, 256, 0, stream>>>(zhi, zlo, outf);
}

// Round 5
// 250.468 us; speedup vs baseline: 1.7621x; 1.1061x over previous
//
#include <hip/hip_runtime.h>
#include <math.h>

#define N_NODES 8192
#define N_EDGES 262144
#define DIM 256
#define OUTD 64

typedef __bf16 bf16x8 __attribute__((ext_vector_type(8)));
typedef float f32x4 __attribute__((ext_vector_type(4)));
typedef unsigned short u16;
typedef u16 u16x4 __attribute__((ext_vector_type(4)));

// round-to-nearest-even split: x = hi + lo, both bf16
__device__ inline void bsplit(float x, u16& h, u16& l) {
    unsigned u = __float_as_uint(x);
    unsigned hi = (u + 0x7FFFu + ((u >> 16) & 1u)) >> 16;
    float fhi = __uint_as_float(hi << 16);
    float lo = x - fhi;
    unsigned ul = __float_as_uint(lo);
    h = (u16)hi;
    l = (u16)((ul + 0x7FFFu + ((ul >> 16) & 1u)) >> 16);
}

// ---------------- CSR build ----------------

__global__ __launch_bounds__(256) void hist_kernel(const int* __restrict__ dst,
                                                   int* __restrict__ cnt) {
    int e = blockIdx.x * 256 + threadIdx.x;
    if (e < N_EDGES) atomicAdd(&cnt[dst[e]], 1);
}

__global__ __launch_bounds__(256) void scan_dinv_kernel(const int* __restrict__ cnt,
                                                        int* __restrict__ off,
                                                        float* __restrict__ dinv) {
    __shared__ int sums[256];
    int tid = threadIdx.x;
    int base = tid * 32;
    int local[32];
    int s = 0;
#pragma unroll
    for (int i = 0; i < 32; ++i) {
        int c = cnt[base + i];
        local[i] = s; s += c;
        dinv[base + i] = rsqrtf((float)(c + 1));
    }
    sums[tid] = s;
    __syncthreads();
    for (int d = 1; d < 256; d <<= 1) {
        int v = (tid >= d) ? sums[tid - d] : 0;
        __syncthreads();
        sums[tid] += v;
        __syncthreads();
    }
    int pre = (tid == 0) ? 0 : sums[tid - 1];
#pragma unroll
    for (int i = 0; i < 32; ++i) off[base + i] = pre + local[i];
    if (tid == 255) off[N_NODES] = pre + s;
}

__global__ __launch_bounds__(256) void fill_kernel(const int* __restrict__ src,
                                                   const int* __restrict__ dst,
                                                   const int* __restrict__ off,
                                                   int* __restrict__ cursor,
                                                   int* __restrict__ csr_src) {
    int e = blockIdx.x * 256 + threadIdx.x;
    if (e < N_EDGES) {
        int d = dst[e];
        int p = atomicAdd(&cursor[d], 1);
        csr_src[off[d] + p] = src[e];
    }
}

// ---------------- weight transpose + split ----------------

__global__ __launch_bounds__(256) void wsplit_kernel(const float* __restrict__ mlp_w,
                                                     const float* __restrict__ w1,
                                                     const float* __restrict__ w2,
                                                     const float* __restrict__ wm,
                                                     const float* __restrict__ wl,
                                                     u16* __restrict__ wtm_hi, u16* __restrict__ wtm_lo,
                                                     u16* __restrict__ wt1_hi, u16* __restrict__ wt1_lo,
                                                     u16* __restrict__ wt2_hi, u16* __restrict__ wt2_lo,
                                                     u16* __restrict__ wth_hi, u16* __restrict__ wth_lo) {
    const int z = blockIdx.z;
    const float* W; u16 *hi, *lo; int N, rowoff;
    if (z == 0)      { W = mlp_w; hi = wtm_hi; lo = wtm_lo; N = 256; rowoff = 0; }
    else if (z == 1) { W = w1;    hi = wt1_hi; lo = wt1_lo; N = 256; rowoff = 0; }
    else if (z == 2) { W = w2;    hi = wt2_hi; lo = wt2_lo; N = 256; rowoff = 0; }
    else if (z == 3) { W = wm;    hi = wth_hi; lo = wth_lo; N = 64;  rowoff = 0; }
    else             { W = wl;    hi = wth_hi; lo = wth_lo; N = 64;  rowoff = 64; }
    if (blockIdx.x * 64 >= N) return;

    const int k0 = blockIdx.y * 64, n0 = blockIdx.x * 64;
    const int tid = threadIdx.x;
    __shared__ float lds[64][68];
#pragma unroll
    for (int it = 0; it < 4; ++it) {
        int slot = tid + it * 256;
        int r = slot >> 4;
        int c4 = (slot & 15) * 4;
        float4 v = *reinterpret_cast<const float4*>(&W[(size_t)(k0 + r) * N + n0 + c4]);
        lds[r][c4] = v.x; lds[r][c4 + 1] = v.y; lds[r][c4 + 2] = v.z; lds[r][c4 + 3] = v.w;
    }
    __syncthreads();
#pragma unroll
    for (int it = 0; it < 4; ++it) {
        int slot = tid + it * 256;
        int n = slot >> 4;
        int k4 = (slot & 15) * 4;
        u16x4 h4, l4;
#pragma unroll
        for (int j = 0; j < 4; ++j) {
            u16 h, l;
            bsplit(lds[k4 + j][n], h, l);
            h4[j] = h; l4[j] = l;
        }
        size_t o = (size_t)(rowoff + n0 + n) * 256 + k0 + k4;
        *reinterpret_cast<u16x4*>(&hi[o]) = h4;
        *reinterpret_cast<u16x4*>(&lo[o]) = l4;
    }
}

// ---------------- split x into hi/lo bf16 ----------------

__global__ __launch_bounds__(256) void split_x_kernel(const float* __restrict__ x,
                                                      u16* __restrict__ xhi,
                                                      u16* __restrict__ xlo) {
    int i = blockIdx.x * 256 + threadIdx.x;
    float4 v = *reinterpret_cast<const float4*>(&x[(size_t)i * 4]);
    float xs[4] = {v.x, v.y, v.z, v.w};
    u16x4 h4, l4;
#pragma unroll
    for (int j = 0; j < 4; ++j) { u16 h, l; bsplit(xs[j], h, l); h4[j] = h; l4[j] = l; }
    *reinterpret_cast<u16x4*>(&xhi[(size_t)i * 4]) = h4;
    *reinterpret_cast<u16x4*>(&xlo[(size_t)i * 4]) = l4;
}

// ---------------- split-bf16 MFMA GEMM ----------------
// C = A[M,256] @ W[256,N]; dscale (optional) row-scales the f32 output (GCN prescale).

template <int MT, int NT, bool OSPLIT>
__global__ __launch_bounds__(256) void gemm_mfma(const u16* __restrict__ Ahi,
                                                 const u16* __restrict__ Alo,
                                                 const u16* __restrict__ Bhi,
                                                 const u16* __restrict__ Blo,
                                                 const float* __restrict__ bias,
                                                 const float* __restrict__ dscale,
                                                 float* __restrict__ Cf,
                                                 u16* __restrict__ Chi,
                                                 u16* __restrict__ Clo,
                                                 int ldc) {
    const int tid = threadIdx.x;
    const int lane = tid & 63, w = tid >> 6;
    const int lr = lane & 15, kq = lane >> 4;
    const int row0 = (blockIdx.y * 4 + w) * (MT * 16);
    const int col0 = blockIdx.x * (NT * 16);

    f32x4 acc[MT][NT];
#pragma unroll
    for (int m = 0; m < MT; ++m)
#pragma unroll
        for (int n = 0; n < NT; ++n) acc[m][n] = (f32x4){0.f, 0.f, 0.f, 0.f};

#pragma unroll
    for (int kt = 0; kt < 8; ++kt) {
        const int k0 = kt * 32 + kq * 8;
        bf16x8 ah[MT], al[MT];
#pragma unroll
        for (int m = 0; m < MT; ++m) {
            size_t o = (size_t)(row0 + m * 16 + lr) * 256 + k0;
            ah[m] = *reinterpret_cast<const bf16x8*>(&Ahi[o]);
            al[m] = *reinterpret_cast<const bf16x8*>(&Alo[o]);
        }
        bf16x8 bh[NT], bl[NT];
#pragma unroll
        for (int n = 0; n < NT; ++n) {
            size_t o = (size_t)(col0 + n * 16 + lr) * 256 + k0;
            bh[n] = *reinterpret_cast<const bf16x8*>(&Bhi[o]);
            bl[n] = *reinterpret_cast<const bf16x8*>(&Blo[o]);
        }
#pragma unroll
        for (int m = 0; m < MT; ++m)
#pragma unroll
            for (int n = 0; n < NT; ++n) {
                acc[m][n] = __builtin_amdgcn_mfma_f32_16x16x32_bf16(ah[m], bh[n], acc[m][n], 0, 0, 0);
                acc[m][n] = __builtin_amdgcn_mfma_f32_16x16x32_bf16(ah[m], bl[n], acc[m][n], 0, 0, 0);
                acc[m][n] = __builtin_amdgcn_mfma_f32_16x16x32_bf16(al[m], bh[n], acc[m][n], 0, 0, 0);
            }
    }

    // C/D layout: col = lr, row = kq*4 + r
#pragma unroll
    for (int m = 0; m < MT; ++m) {
        float scl[4];
#pragma unroll
        for (int r = 0; r < 4; ++r) {
            int row = row0 + m * 16 + kq * 4 + r;
            scl[r] = dscale ? dscale[row] : 1.f;
        }
#pragma unroll
        for (int n = 0; n < NT; ++n) {
            int col = col0 + n * 16 + lr;
            float b = bias ? bias[col] : 0.f;
#pragma unroll
            for (int r = 0; r < 4; ++r) {
                int row = row0 + m * 16 + kq * 4 + r;
                float v = (acc[m][n][r] + b) * scl[r];
                size_t o = (size_t)row * ldc + col;
                if (OSPLIT) {
                    u16 h, l; bsplit(v, h, l);
                    Chi[o] = h; Clo[o] = l;
                } else {
                    Cf[o] = v;
                }
            }
        }
    }
}

// ---------------- GCN aggregation (F=256) over prescaled xw' ----------------
// xwp[r] = dinv[r] * (h@W)[r]; out = relu(dinv[d]*(sum_nb xwp[s] + xwp[d]) + bias), split.

__global__ __launch_bounds__(256) void gcn_agg_kernel(const float* __restrict__ xwp,
                                                      const float* __restrict__ dinv,
                                                      const int* __restrict__ off,
                                                      const int* __restrict__ csr_src,
                                                      const float* __restrict__ bias,
                                                      u16* __restrict__ ohi,
                                                      u16* __restrict__ olo) {
    const int d = blockIdx.x;
    const int f = threadIdx.x;
    __shared__ int sidx[64];
    const int beg = off[d], end = off[d + 1];
    float acc = xwp[(size_t)d * DIM + f];   // self term
    int e = beg;
    while (e < end) {
        int m = end - e; if (m > 64) m = 64;
        __syncthreads();
        if (threadIdx.x < m) sidx[threadIdx.x] = csr_src[e + threadIdx.x];
        __syncthreads();
        int i = 0;
        for (; i + 4 <= m; i += 4) {
            int s0 = sidx[i], s1 = sidx[i + 1], s2 = sidx[i + 2], s3 = sidx[i + 3];
            float v0 = xwp[(size_t)s0 * DIM + f];
            float v1 = xwp[(size_t)s1 * DIM + f];
            float v2 = xwp[(size_t)s2 * DIM + f];
            float v3 = xwp[(size_t)s3 * DIM + f];
            acc += v0 + v1 + v2 + v3;
        }
        for (; i < m; ++i) acc += xwp[(size_t)sidx[i] * DIM + f];
        e += m;
    }
    float v = fmaf(dinv[d], acc, bias[f]);
    v = fmaxf(v, 0.f);
    u16 h, l; bsplit(v, h, l);
    ohi[(size_t)d * DIM + f] = h;
    olo[(size_t)d * DIM + f] = l;
}

// ---------------- fused head over prescaled xwcat' [N][128] ----------------

__global__ __launch_bounds__(256) void head_kernel(const float* __restrict__ xwp,
                                                   const float* __restrict__ dinv,
                                                   const int* __restrict__ off,
                                                   const int* __restrict__ csr_src,
                                                   const float* __restrict__ b_mean,
                                                   const float* __restrict__ b_logstd,
                                                   const float* __restrict__ noise,
                                                   u16* __restrict__ zhi,
                                                   u16* __restrict__ zlo) {
    const int tid = threadIdx.x;
    const int half = tid >> 7;
    const int d = blockIdx.x * 2 + half;
    const int head = (tid >> 6) & 1;
    const int f = tid & 63;
    const int fc = head * 64 + f;
    const float bias = head ? b_logstd[f] : b_mean[f];

    // uniform chunk count across the whole block (both halves)
    const int b0 = off[blockIdx.x * 2];
    const int b1 = off[blockIdx.x * 2 + 1];
    const int b2 = off[blockIdx.x * 2 + 2];
    const int beg = half ? b1 : b0;
    const int end = half ? b2 : b1;
    int d0 = b1 - b0, d1 = b2 - b1;
    int maxdeg = d0 > d1 ? d0 : d1;
    int nch = (maxdeg + 63) >> 6;

    __shared__ int sidx[2][64];
    float acc = xwp[(size_t)d * 128 + fc];  // self term
    int e = beg;
    for (int c = 0; c < nch; ++c) {
        int m = end - e; if (m > 64) m = 64; if (m < 0) m = 0;
        __syncthreads();
        int lt = tid & 127;
        if (lt < m) sidx[half][lt] = csr_src[e + lt];
        __syncthreads();
        int i = 0;
        for (; i + 4 <= m; i += 4) {
            int s0 = sidx[half][i], s1 = sidx[half][i + 1];
            int s2 = sidx[half][i + 2], s3 = sidx[half][i + 3];
            float v0 = xwp[(size_t)s0 * 128 + fc];
            float v1 = xwp[(size_t)s1 * 128 + fc];
            float v2 = xwp[(size_t)s2 * 128 + fc];
            float v3 = xwp[(size_t)s3 * 128 + fc];
            acc += v0 + v1 + v2 + v3;
        }
        for (; i < m; ++i) acc += xwp[(size_t)sidx[half][i] * 128 + fc];
        e += m;
    }
    float v = fmaf(dinv[d], acc, bias);
    v = fmaxf(v, 0.f);

    __shared__ float sh[2][2][64];
    sh[half][head][f] = v;
    __syncthreads();

    if (head == 0) {
        float ls = sh[half][1][f];
        float z = fmaf(noise[(size_t)d * OUTD + f], expf(ls), v);
        u16 h, l; bsplit(z, h, l);
        zhi[(size_t)d * OUTD + f] = h;
        zlo[(size_t)d * OUTD + f] = l;
    }
}

// ---------------- decoder: out = triu(sigmoid(z z^T), 1), split-bf16 MFMA ----------------
// 33 KB LDS (two-pass transpose) -> 4 blocks/CU.

__global__ __launch_bounds__(256) void decode_mfma_kernel(const u16* __restrict__ zhi,
                                                          const u16* __restrict__ zlo,
                                                          float* __restrict__ out) {
    const int bi = blockIdx.y, bj = blockIdx.x;
    const int tid = threadIdx.x;

    if (bj < bi) {
        const float4 zero = {0.f, 0.f, 0.f, 0.f};
        size_t base = (size_t)bi * 128 * N_NODES + (size_t)bj * 128;
#pragma unroll 4
        for (int t = 0; t < 16; ++t) {
            int slot = tid + t * 256;
            int r = slot >> 5;
            int c = (slot & 31) * 4;
            *reinterpret_cast<float4*>(&out[base + (size_t)r * N_NODES + c]) = zero;
        }
        return;
    }

    __shared__ float sh[64][132];

    const int lane = tid & 63;
    const int w = tid >> 6;
    const int lr = lane & 15;
    const int kq = lane >> 4;

    f32x4 acc[2][8];
#pragma unroll
    for (int m = 0; m < 2; ++m)
#pragma unroll
        for (int n = 0; n < 8; ++n) acc[m][n] = (f32x4){0.f, 0.f, 0.f, 0.f};

    bf16x8 ah[2][2], al[2][2];
#pragma unroll
    for (int m = 0; m < 2; ++m)
#pragma unroll
        for (int kt = 0; kt < 2; ++kt) {
            size_t idx = (size_t)(bi * 128 + w * 32 + m * 16 + lr) * OUTD + kt * 32 + kq * 8;
            ah[m][kt] = *reinterpret_cast<const bf16x8*>(&zhi[idx]);
            al[m][kt] = *reinterpret_cast<const bf16x8*>(&zlo[idx]);
        }

#pragma unroll
    for (int n = 0; n < 8; ++n) {
        bf16x8 bh[2], bl[2];
#pragma unroll
        for (int kt = 0; kt < 2; ++kt) {
            size_t idx = (size_t)(bj * 128 + n * 16 + lr) * OUTD + kt * 32 + kq * 8;
            bh[kt] = *reinterpret_cast<const bf16x8*>(&zhi[idx]);
            bl[kt] = *reinterpret_cast<const bf16x8*>(&zlo[idx]);
        }
#pragma unroll
        for (int m = 0; m < 2; ++m)
#pragma unroll
            for (int kt = 0; kt < 2; ++kt) {
                acc[m][n] = __builtin_amdgcn_mfma_f32_16x16x32_bf16(ah[m][kt], bh[kt], acc[m][n], 0, 0, 0);
                acc[m][n] = __builtin_amdgcn_mfma_f32_16x16x32_bf16(ah[m][kt], bl[kt], acc[m][n], 0, 0, 0);
                acc[m][n] = __builtin_amdgcn_mfma_f32_16x16x32_bf16(al[m][kt], bh[kt], acc[m][n], 0, 0, 0);
            }
    }

    const bool diag = (bi == bj);
#pragma unroll
    for (int m = 0; m < 2; ++m) {
        __syncthreads();
        // pass m: local row = w*16 + kq*4 + r  (global tile row = w*32 + m*16 + kq*4 + r)
#pragma unroll
        for (int n = 0; n < 8; ++n)
#pragma unroll
            for (int r = 0; r < 4; ++r)
                sh[w * 16 + kq * 4 + r][n * 16 + lr] = acc[m][n][r];
        __syncthreads();
#pragma unroll
        for (int it = 0; it < 8; ++it) {
            int slot = tid + it * 256;          // 2048 slots = 64 rows x 32 float4
            int lrow = slot >> 5;
            int col = (slot & 31) * 4;
            int growt = ((lrow >> 4) << 5) + m * 16 + (lrow & 15);
            int gi = bi * 128 + growt;
            int gj = bj * 128 + col;
            float4 v = *reinterpret_cast<const float4*>(&sh[lrow][col]);
            float vals[4] = {v.x, v.y, v.z, v.w};
#pragma unroll
            for (int j = 0; j < 4; ++j) {
                float s = 1.f / (1.f + __expf(-vals[j]));
                if (diag && (gj + j) <= gi) s = 0.f;
                vals[j] = s;
            }
            float4 o = {vals[0], vals[1], vals[2], vals[3]};
            *reinterpret_cast<float4*>(&out[(size_t)gi * N_NODES + gj]) = o;
        }
    }
}

// ---------------- launch ----------------

extern "C" void kernel_launch(void* const* d_in, const int* in_sizes, int n_in,
                              void* d_out, int out_size, void* d_ws, size_t ws_size,
                              hipStream_t stream) {
    const float* x        = (const float*)d_in[0];
    const int*   ei       = (const int*)d_in[1];
    const float* noise    = (const float*)d_in[2];
    const float* mlp_w    = (const float*)d_in[3];
    const float* mlp_b    = (const float*)d_in[4];
    const float* w1       = (const float*)d_in[5];
    const float* b1       = (const float*)d_in[6];
    const float* w2       = (const float*)d_in[7];
    const float* b2       = (const float*)d_in[8];
    const float* w_mean   = (const float*)d_in[9];
    const float* b_mean   = (const float*)d_in[10];
    const float* w_logstd = (const float*)d_in[11];
    const float* b_logstd = (const float*)d_in[12];
    float* outf = (float*)d_out;

    // ---- scratch in d_out (fully overwritten by decode at the end) ----
    const size_t S = (size_t)N_NODES * DIM;            // 2,097,152 floats
    u16* h0hi = (u16*)outf;
    u16* h0lo = h0hi + S;                              // [0, S)
    float* xw = outf + S;                              // [S, 2S)
    u16* h1hi = (u16*)(outf + 2 * S);
    u16* h1lo = h1hi + S;                              // [2S, 3S)
    u16* h2hi = h0hi;                                  // reuse h0 region
    u16* h2lo = h0lo;
    float* xwcat = outf + 3 * S;                       // [3S, 3.5S) f32 [8192][128]
    float* dinv = outf + 3 * S + S / 2;
    int* cnt     = (int*)(dinv + N_NODES);
    int* cursor  = cnt + N_NODES;
    int* off     = cursor + N_NODES;                   // 8193 used, pad 8704
    int* csr_src = off + 8704;
    u16* wt = (u16*)(outf + 4 * S);
    u16* wtm_hi = wt;               u16* wtm_lo = wt + 65536;
    u16* wt1_hi = wt + 131072;      u16* wt1_lo = wt + 196608;
    u16* wt2_hi = wt + 262144;      u16* wt2_lo = wt + 327680;
    u16* wth_hi = wt + 393216;      u16* wth_lo = wt + 425984;
    u16* xhi = (u16*)(outf + 5 * S);
    u16* xlo = xhi + S;                                // [5S, 6S)

    u16* zhi = (u16*)d_ws;
    u16* zlo = zhi + (size_t)N_NODES * OUTD;

    const int* srcI = ei;
    const int* dstI = ei + N_EDGES;

    hipMemsetAsync(cnt, 0, 2 * N_NODES * sizeof(int), stream);
    hist_kernel<<<N_EDGES / 256, 256, 0, stream>>>(dstI, cnt);
    scan_dinv_kernel<<<1, 256, 0, stream>>>(cnt, off, dinv);
    fill_kernel<<<N_EDGES / 256, 256, 0, stream>>>(srcI, dstI, off, cursor, csr_src);

    wsplit_kernel<<<dim3(4, 4, 5), 256, 0, stream>>>(mlp_w, w1, w2, w_mean, w_logstd,
                                                     wtm_hi, wtm_lo, wt1_hi, wt1_lo,
                                                     wt2_hi, wt2_lo, wth_hi, wth_lo);
    split_x_kernel<<<(N_NODES * DIM / 4) / 256, 256, 0, stream>>>(x, xhi, xlo);

    dim3 g256(4, 64);
    // h0 = x @ mlp_w + mlp_b (split out, no prescale)
    gemm_mfma<2, 4, true><<<g256, 256, 0, stream>>>(xhi, xlo, wtm_hi, wtm_lo, mlp_b, nullptr,
                                                    nullptr, h0hi, h0lo, DIM);
    // xw1' = dinv * (h0 @ w1)
    gemm_mfma<2, 4, false><<<g256, 256, 0, stream>>>(h0hi, h0lo, wt1_hi, wt1_lo, nullptr, dinv,
                                                     xw, nullptr, nullptr, DIM);
    gcn_agg_kernel<<<N_NODES, 256, 0, stream>>>(xw, dinv, off, csr_src, b1, h1hi, h1lo);
    // xw2' = dinv * (h1 @ w2)
    gemm_mfma<2, 4, false><<<g256, 256, 0, stream>>>(h1hi, h1lo, wt2_hi, wt2_lo, nullptr, dinv,
                                                     xw, nullptr, nullptr, DIM);
    gcn_agg_kernel<<<N_NODES, 256, 0, stream>>>(xw, dinv, off, csr_src, b2, h2hi, h2lo);
    // xwcat' = dinv * (h2 @ [Wm|Wl])  -> [8192][128]
    gemm_mfma<1, 4, false><<<dim3(2, 128), 256, 0, stream>>>(h2hi, h2lo, wth_hi, wth_lo, nullptr, dinv,
                                                             xwcat, nullptr, nullptr, 128);
    head_kernel<<<N_NODES / 2, 256, 0, stream>>>(xwcat, dinv, off, csr_src,
                                                 b_mean, b_logstd, noise, zhi, zlo);
    dim3 gd(N_NODES / 128, N_NODES / 128);
    decode_mfma_kernel<<<gd, 256, 0, stream>>>(zhi, zlo, outf);
}